// Round 9
// baseline (775.630 us; speedup 1.0000x reference)
//
#include <hip/hip_runtime.h>
#include <hip/hip_bf16.h>

typedef unsigned short u16;
typedef unsigned int u32;
typedef __attribute__((ext_vector_type(8))) short bf16x8;
typedef __attribute__((ext_vector_type(4))) float f32x4;

#define MFMA16(a, b, c) __builtin_amdgcn_mfma_f32_16x16x32_bf16(a, b, c, 0, 0, 0)

// fold of softmax scale into Q projection: exp(s/8) = 2^(s*0.125*log2(e))
#define QSCALE 0.18033688011112042f

__device__ inline u16 f2b(float f) {
    union { float f; unsigned int i; } v;
    v.f = f;
    unsigned int r = v.i + 0x7fffu + ((v.i >> 16) & 1u);
    return (u16)(r >> 16);
}
__device__ inline u32 fbits(float f) {
    union { float f; u32 i; } v; v.f = f; return v.i;
}
// pack two fp32 -> [bf16(f0) | bf16(f1)<<16], truncation, 1 v_perm_b32
__device__ inline u32 pack2_trunc(float f0, float f1) {
    return __builtin_amdgcn_perm(fbits(f1), fbits(f0), 0x07060302u);
}

// async global->LDS, 16B per lane (wave-uniform base + lane*16 dest).
__device__ inline void glds16(const u16* g, u16* l) {
    __builtin_amdgcn_global_load_lds(
        (const __attribute__((address_space(1))) unsigned int*)g,
        (__attribute__((address_space(3))) unsigned int*)l, 16, 0, 0);
}

// fp32 -> bf16 (RNE), 8 elements per thread.
__global__ __launch_bounds__(256) void cvt_f32_bf16(
    const float* __restrict__ x, u16* __restrict__ y, int n)
{
    int i = (blockIdx.x * 256 + threadIdx.x) * 8;
    if (i >= n) return;
    float4 a = *(const float4*)(x + i);
    float4 b = *(const float4*)(x + i + 4);
    u16 o[8] = { f2b(a.x), f2b(a.y), f2b(a.z), f2b(a.w),
                 f2b(b.x), f2b(b.y), f2b(b.z), f2b(b.w) };
    *(uint4*)(y + i) = *(uint4*)o;
}

// Shared GEMM K-loop body: BK=64 as two BK=32 sub-tiles (separate LDS regions,
// preserving glds16 lane-contiguity per sub-tile; read pattern = m97's).
// 32 MFMAs per barrier-pair -> halves per-iter drain overhead vs BK=32.
#define GEMM_KLOOP(Aptr, Bptr)                                                  \
    for (int k0 = 0; k0 < K; k0 += 64) {                                        \
        __syncthreads();                                                        \
        {                                                                       \
            int ra = wave * 16 + r0;                                            \
            _Pragma("unroll")                                                   \
            for (int s = 0; s < 2; ++s) {                                       \
                int ks0 = k0 + s * 32;                                          \
                glds16(&Aptr[(size_t)(m0 + ra) * K + ks0 + c0],                 \
                       &As[s][ra * 32 + c0]);                                   \
                glds16(&Aptr[(size_t)(m0 + 64 + ra) * K + ks0 + c0],            \
                       &As[s][(64 + ra) * 32 + c0]);                            \
                glds16(&Bptr[(size_t)(n0 + ra) * K + ks0 + c0],                 \
                       &Bs[s][ra * 32 + c0]);                                   \
                glds16(&Bptr[(size_t)(n0 + 64 + ra) * K + ks0 + c0],            \
                       &Bs[s][(64 + ra) * 32 + c0]);                            \
            }                                                                   \
        }                                                                       \
        __syncthreads();                                                        \
        _Pragma("unroll")                                                       \
        for (int s = 0; s < 2; ++s) {                                           \
            bf16x8 af[4], bfr[4];                                               \
            _Pragma("unroll")                                                   \
            for (int mi = 0; mi < 4; ++mi)                                      \
                af[mi] = *(const bf16x8*)(&As[s][(wm + mi * 16 + l16) * 32 + quad * 8]); \
            _Pragma("unroll")                                                   \
            for (int ni = 0; ni < 4; ++ni)                                      \
                bfr[ni] = *(const bf16x8*)(&Bs[s][(wn + ni * 16 + l16) * 32 + quad * 8]); \
            _Pragma("unroll")                                                   \
            for (int mi = 0; mi < 4; ++mi)                                      \
                _Pragma("unroll")                                               \
                for (int ni = 0; ni < 4; ++ni)                                  \
                    acc[mi][ni] = MFMA16(af[mi], bfr[ni], acc[mi][ni]);         \
        }                                                                       \
    }

// Fused Q/K/V projections. sel = blockIdx.y/8 picks {src, weight, bias, dst, scale}.
__global__ __launch_bounds__(256) void gemm_proj(
    const u16* __restrict__ qb, const u16* __restrict__ vb,
    const u16* __restrict__ wqb, const u16* __restrict__ wkb,
    const u16* __restrict__ wvb,
    const float* __restrict__ bq, const float* __restrict__ bk,
    const float* __restrict__ bv,
    u16* __restrict__ Qp, u16* __restrict__ Kp, u16* __restrict__ Vp,
    int M, int K)
{
    const int sel = blockIdx.y >> 3;
    const int n0 = (blockIdx.y & 7) * 128;
    const u16* A = sel ? vb : qb;
    const u16* W = sel == 0 ? wqb : (sel == 1 ? wkb : wvb);
    const float* bias = sel == 0 ? bq : (sel == 1 ? bk : bv);
    u16* C = sel == 0 ? Qp : (sel == 1 ? Kp : Vp);
    const float cscale = sel == 0 ? QSCALE : 1.0f;

    __shared__ __align__(16) u16 As[2][128 * 32];
    __shared__ __align__(16) u16 Bs[2][128 * 32];

    const int tid  = threadIdx.x;
    const int wave = tid >> 6, lane = tid & 63;
    const int quad = lane >> 4, l16 = lane & 15;
    const int m0 = blockIdx.x * 128;
    const int wm = (wave >> 1) * 64, wn = (wave & 1) * 64;
    const int r0 = lane >> 2;
    const int c0 = (lane & 3) * 8;

    f32x4 acc[4][4] = {};

    GEMM_KLOOP(A, W)

#pragma unroll
    for (int mi = 0; mi < 4; ++mi) {
#pragma unroll
        for (int ni = 0; ni < 4; ++ni) {
            int col = n0 + wn + ni * 16 + l16;
            float bv2 = bias[col];
#pragma unroll
            for (int r = 0; r < 4; ++r) {
                int row = m0 + wm + mi * 16 + quad * 4 + r;
                C[(size_t)row * 1024 + col] = f2b((acc[mi][ni][r] + bv2) * cscale);
            }
        }
    }
}

// Output GEMM: C[M,N](fp32) = A[M,K](bf16) @ B[N,K]^T(bf16) + bias.
__global__ __launch_bounds__(256) void gemm_out(
    const u16* __restrict__ A, const u16* __restrict__ B,
    const float* __restrict__ bias, float* __restrict__ C,
    int M, int N, int K)
{
    __shared__ __align__(16) u16 As[2][128 * 32];
    __shared__ __align__(16) u16 Bs[2][128 * 32];

    const int tid  = threadIdx.x;
    const int wave = tid >> 6, lane = tid & 63;
    const int quad = lane >> 4, l16 = lane & 15;
    const int m0 = blockIdx.x * 128, n0 = blockIdx.y * 128;
    const int wm = (wave >> 1) * 64, wn = (wave & 1) * 64;
    const int r0 = lane >> 2;
    const int c0 = (lane & 3) * 8;

    f32x4 acc[4][4] = {};

    GEMM_KLOOP(A, B)

#pragma unroll
    for (int mi = 0; mi < 4; ++mi) {
#pragma unroll
        for (int ni = 0; ni < 4; ++ni) {
            int col = n0 + wn + ni * 16 + l16;
            float bv = bias[col];
#pragma unroll
            for (int r = 0; r < 4; ++r) {
                int row = m0 + wm + mi * 16 + quad * 4 + r;
                C[(size_t)row * N + col] = acc[mi][ni][r] + bv;
            }
        }
    }
}

// Transpose Vp[b*2048+l][1024] -> VT[(b*1024+d)*2048 + l].  64x64 bf16 tiles.
__global__ __launch_bounds__(256) void transpose_v(
    const u16* __restrict__ Vp, u16* __restrict__ VT)
{
    __shared__ u16 T[64 * 66];
    const int tid = threadIdx.x;
    const int l0 = blockIdx.x * 64, d0 = blockIdx.y * 64, b = blockIdx.z;

#pragma unroll
    for (int i = 0; i < 2; ++i) {
        int ch = tid + i * 256;
        int lrow = ch >> 3, c8 = (ch & 7) * 8;
        uint4 vv = *(const uint4*)(&Vp[((size_t)b * 2048 + l0 + lrow) * 1024 + d0 + c8]);
        const u16* vp = (const u16*)&vv;
#pragma unroll
        for (int j = 0; j < 8; ++j) T[lrow * 66 + c8 + j] = vp[j];
    }
    __syncthreads();
#pragma unroll
    for (int i = 0; i < 2; ++i) {
        int ch = tid + i * 256;
        int drow = ch >> 3, l8 = (ch & 7) * 8;
        u16 o[8];
#pragma unroll
        for (int j = 0; j < 8; ++j) o[j] = T[(l8 + j) * 66 + drow];
        *(uint4*)(&VT[((size_t)b * 1024 + d0 + drow) * 2048 + l0 + l8]) = *(uint4*)o;
    }
}

// Flash attention (Q pre-scaled so p = exp2(S); max-free). S computed transposed
// (mfma(kf,qf)). P round-trips LDS in TWO 32-k chunks through a HALF-SIZE Ps
// (64x36/wave): LDS 57.9->39.2 KB => 4 blocks/CU (was 2). Rowsum via 5th
// all-ones V^T tile. Block = 4 waves x 64 q-rows, BK=64.
__global__ __launch_bounds__(256, 4) void attn(
    const u16* __restrict__ Q, const u16* __restrict__ K,
    const u16* __restrict__ VT, u16* __restrict__ O,
    int LQ, int LK)
{
    const int tid  = threadIdx.x;
    const int wave = tid >> 6, lane = tid & 63;
    const int quad = lane >> 4, l16 = lane & 15;
    const int q0 = blockIdx.x * 256;
    const int bh = blockIdx.y;
    const int b = bh >> 4, h = bh & 15;
    const size_t qbase = ((size_t)b * LQ + q0) * 1024 + h * 64;
    const size_t kbase = ((size_t)b * LK) * 1024 + h * 64;
    const size_t vtbase = ((size_t)b * 1024 + h * 64) * 2048;

    __shared__ __align__(16) u16 Ks[64 * 72];        // [krow][d]
    __shared__ __align__(16) u16 VTs[80 * 72];       // [d][krow]; rows 64..79 = 1.0
    __shared__ __align__(16) u16 Ps[4][64 * 36];     // per-wave P [q][k-chunk of 32]

    for (int i = tid; i < 16 * 72; i += 256) VTs[64 * 72 + i] = 0x3F80;

    bf16x8 qf[4][2];
#pragma unroll
    for (int mi = 0; mi < 4; ++mi)
#pragma unroll
        for (int ks = 0; ks < 2; ++ks)
            qf[mi][ks] = *(const bf16x8*)(
                &Q[qbase + (size_t)(wave * 64 + mi * 16 + l16) * 1024 + ks * 32 + quad * 8]);

    f32x4 oacc[4][5] = {};   // [q-tile][4 d-tiles + 1 rowsum tile]

    for (int kt = 0; kt < LK; kt += 64) {
        __syncthreads();
#pragma unroll
        for (int i = 0; i < 2; ++i) {
            int ch = tid + i * 256;
            int row = ch >> 3, c8 = (ch & 7) * 8;
            *(uint4*)(&Ks[row * 72 + c8]) =
                *(const uint4*)(&K[kbase + (size_t)(kt + row) * 1024 + c8]);
            *(uint4*)(&VTs[row * 72 + c8]) =
                *(const uint4*)(&VT[vtbase + (size_t)row * 2048 + kt + c8]);
        }
        __syncthreads();

        // S^T tiles: st[ni][mi]; lane (quad,l16) reg r holds
        // S[q = mi*16+l16][k = ni*16+quad*4+r]
        f32x4 st[4][4] = {};
#pragma unroll
        for (int ks = 0; ks < 2; ++ks) {
            bf16x8 kf[4];
#pragma unroll
            for (int ni = 0; ni < 4; ++ni)
                kf[ni] = *(const bf16x8*)(&Ks[(ni * 16 + l16) * 72 + ks * 32 + quad * 8]);
#pragma unroll
            for (int ni = 0; ni < 4; ++ni)
#pragma unroll
                for (int mi = 0; mi < 4; ++mi)
                    st[ni][mi] = MFMA16(kf[ni], qf[mi][ks], st[ni][mi]);
        }

        // two 32-k chunks: pack P for chunk kh, then PV step kh (Ps reused)
#pragma unroll
        for (int kh = 0; kh < 2; ++kh) {
#pragma unroll
            for (int mi = 0; mi < 4; ++mi)
#pragma unroll
                for (int nj = 0; nj < 2; ++nj) {
                    int ni = kh * 2 + nj;
                    float p0 = __builtin_amdgcn_exp2f(st[ni][mi][0]);
                    float p1 = __builtin_amdgcn_exp2f(st[ni][mi][1]);
                    float p2 = __builtin_amdgcn_exp2f(st[ni][mi][2]);
                    float p3 = __builtin_amdgcn_exp2f(st[ni][mi][3]);
                    uint2 w;
                    w.x = pack2_trunc(p0, p1);
                    w.y = pack2_trunc(p2, p3);
                    *(uint2*)(&Ps[wave][(mi * 16 + l16) * 36 + nj * 16 + quad * 4]) = w;
                }
            // Ps wave-private: lgkmcnt orders wave-local LDS; no barrier.
            bf16x8 vf[5];
#pragma unroll
            for (int nd = 0; nd < 5; ++nd)
                vf[nd] = *(const bf16x8*)(&VTs[(nd * 16 + l16) * 72 + kh * 32 + quad * 8]);
#pragma unroll
            for (int mi = 0; mi < 4; ++mi) {
                bf16x8 pf = *(const bf16x8*)(&Ps[wave][(mi * 16 + l16) * 36 + quad * 8]);
#pragma unroll
                for (int nd = 0; nd < 5; ++nd)
                    oacc[mi][nd] = MFMA16(pf, vf[nd], oacc[mi][nd]);
            }
        }
    }

    // epilogue: divide by MFMA-computed row sums, store
#pragma unroll
    for (int mi = 0; mi < 4; ++mi)
#pragma unroll
        for (int r = 0; r < 4; ++r) {
            float inv = 1.0f / oacc[mi][4][r];
            int row = q0 + wave * 64 + mi * 16 + quad * 4 + r;
            size_t rb = ((size_t)b * LQ + row) * 1024 + h * 64;
#pragma unroll
            for (int nd = 0; nd < 4; ++nd)
                O[rb + nd * 16 + l16] = f2b(oacc[mi][nd][r] * inv);
        }
}

extern "C" void kernel_launch(void* const* d_in, const int* in_sizes, int n_in,
                              void* d_out, int out_size, void* d_ws, size_t ws_size,
                              hipStream_t stream) {
    const float* query = (const float*)d_in[0];
    const float* value = (const float*)d_in[1];
    const float* wq = (const float*)d_in[2];
    const float* bq = (const float*)d_in[3];
    const float* wk = (const float*)d_in[4];
    const float* bk = (const float*)d_in[5];
    const float* wv = (const float*)d_in[6];
    const float* bv = (const float*)d_in[7];
    const float* wo = (const float*)d_in[8];
    const float* bo = (const float*)d_in[9];

    const int B = 4, LQ = 2048, LK = 2048, D = 1024;
    const int M = B * LQ;                 // 8192
    const int mat = M * D;                // 8388608
    const int wsz = D * D;                // 1048576

    // ws (u16): qb vb | wqb wkb wvb wob | Qp Kp Vp VT  = 104 MB
    u16* ws  = (u16*)d_ws;
    u16* qb  = ws;
    u16* vb  = qb + mat;
    u16* wqb = vb + mat;
    u16* wkb = wqb + wsz;
    u16* wvb = wkb + wsz;
    u16* wob = wvb + wsz;
    u16* Qp  = wob + wsz;
    u16* Kp  = Qp + mat;
    u16* Vp  = Kp + mat;
    u16* VT  = Vp + mat;
    u16* Cp  = Vp;                        // Vp dead after transpose_v

    dim3 blk(256);

    cvt_f32_bf16<<<dim3(mat / 2048), blk, 0, stream>>>(query, qb, mat);
    cvt_f32_bf16<<<dim3(mat / 2048), blk, 0, stream>>>(value, vb, mat);
    cvt_f32_bf16<<<dim3(wsz / 2048), blk, 0, stream>>>(wq, wqb, wsz);
    cvt_f32_bf16<<<dim3(wsz / 2048), blk, 0, stream>>>(wk, wkb, wsz);
    cvt_f32_bf16<<<dim3(wsz / 2048), blk, 0, stream>>>(wv, wvb, wsz);
    cvt_f32_bf16<<<dim3(wsz / 2048), blk, 0, stream>>>(wo, wob, wsz);

    gemm_proj<<<dim3(M / 128, 24), blk, 0, stream>>>(
        qb, vb, wqb, wkb, wvb, bq, bk, bv, Qp, Kp, Vp, M, D);

    transpose_v<<<dim3(32, 16, 4), blk, 0, stream>>>(Vp, VT);

    attn<<<dim3(LQ / 256, B * 16), blk, 0, stream>>>(Qp, Kp, VT, Cp, LQ, LK);

    gemm_out<<<dim3(M / 128, D / 128), blk, 0, stream>>>(Cp, wob, bo, (float*)d_out, M, D, D);
}

// Round 10
// 388.513 us; speedup vs baseline: 1.9964x; 1.9964x over previous
//
#include <hip/hip_runtime.h>
#include <hip/hip_bf16.h>

typedef unsigned short u16;
typedef unsigned int u32;
typedef __attribute__((ext_vector_type(8))) short bf16x8;
typedef __attribute__((ext_vector_type(4))) float f32x4;

#define MFMA16(a, b, c) __builtin_amdgcn_mfma_f32_16x16x32_bf16(a, b, c, 0, 0, 0)

// fold of softmax scale into Q projection: exp(s/8) = 2^(s*0.125*log2(e))
#define QSCALE 0.18033688011112042f

__device__ inline u16 f2b(float f) {
    union { float f; unsigned int i; } v;
    v.f = f;
    unsigned int r = v.i + 0x7fffu + ((v.i >> 16) & 1u);
    return (u16)(r >> 16);
}
__device__ inline u32 fbits(float f) {
    union { float f; u32 i; } v; v.f = f; return v.i;
}
// pack two fp32 -> [bf16(f0) | bf16(f1)<<16], truncation, 1 v_perm_b32
__device__ inline u32 pack2_trunc(float f0, float f1) {
    return __builtin_amdgcn_perm(fbits(f1), fbits(f0), 0x07060302u);
}

// async global->LDS, 16B per lane (wave-uniform base + lane*16 dest).
__device__ inline void glds16(const u16* g, u16* l) {
    __builtin_amdgcn_global_load_lds(
        (const __attribute__((address_space(1))) unsigned int*)g,
        (__attribute__((address_space(3))) unsigned int*)l, 16, 0, 0);
}

// fp32 -> bf16 (RNE), 8 elements per thread.
__global__ __launch_bounds__(256) void cvt_f32_bf16(
    const float* __restrict__ x, u16* __restrict__ y, int n)
{
    int i = (blockIdx.x * 256 + threadIdx.x) * 8;
    if (i >= n) return;
    float4 a = *(const float4*)(x + i);
    float4 b = *(const float4*)(x + i + 4);
    u16 o[8] = { f2b(a.x), f2b(a.y), f2b(a.z), f2b(a.w),
                 f2b(b.x), f2b(b.y), f2b(b.z), f2b(b.w) };
    *(uint4*)(y + i) = *(uint4*)o;
}

// Shared GEMM K-loop body: BK=64 as two BK=32 sub-tiles (glds16 lane-contiguity
// preserved per sub-tile). 32 MFMAs per barrier-pair. [neutral vs BK=32; kept]
#define GEMM_KLOOP(Aptr, Bptr)                                                  \
    for (int k0 = 0; k0 < K; k0 += 64) {                                        \
        __syncthreads();                                                        \
        {                                                                       \
            int ra = wave * 16 + r0;                                            \
            _Pragma("unroll")                                                   \
            for (int s = 0; s < 2; ++s) {                                       \
                int ks0 = k0 + s * 32;                                          \
                glds16(&Aptr[(size_t)(m0 + ra) * K + ks0 + c0],                 \
                       &As[s][ra * 32 + c0]);                                   \
                glds16(&Aptr[(size_t)(m0 + 64 + ra) * K + ks0 + c0],            \
                       &As[s][(64 + ra) * 32 + c0]);                            \
                glds16(&Bptr[(size_t)(n0 + ra) * K + ks0 + c0],                 \
                       &Bs[s][ra * 32 + c0]);                                   \
                glds16(&Bptr[(size_t)(n0 + 64 + ra) * K + ks0 + c0],            \
                       &Bs[s][(64 + ra) * 32 + c0]);                            \
            }                                                                   \
        }                                                                       \
        __syncthreads();                                                        \
        _Pragma("unroll")                                                       \
        for (int s = 0; s < 2; ++s) {                                           \
            bf16x8 af[4], bfr[4];                                               \
            _Pragma("unroll")                                                   \
            for (int mi = 0; mi < 4; ++mi)                                      \
                af[mi] = *(const bf16x8*)(&As[s][(wm + mi * 16 + l16) * 32 + quad * 8]); \
            _Pragma("unroll")                                                   \
            for (int ni = 0; ni < 4; ++ni)                                      \
                bfr[ni] = *(const bf16x8*)(&Bs[s][(wn + ni * 16 + l16) * 32 + quad * 8]); \
            _Pragma("unroll")                                                   \
            for (int mi = 0; mi < 4; ++mi)                                      \
                _Pragma("unroll")                                               \
                for (int ni = 0; ni < 4; ++ni)                                  \
                    acc[mi][ni] = MFMA16(af[mi], bfr[ni], acc[mi][ni]);         \
        }                                                                       \
    }

// Fused Q/K/V projections. sel = blockIdx.y/8 picks {src, weight, bias, dst, scale}.
__global__ __launch_bounds__(256) void gemm_proj(
    const u16* __restrict__ qb, const u16* __restrict__ vb,
    const u16* __restrict__ wqb, const u16* __restrict__ wkb,
    const u16* __restrict__ wvb,
    const float* __restrict__ bq, const float* __restrict__ bk,
    const float* __restrict__ bv,
    u16* __restrict__ Qp, u16* __restrict__ Kp, u16* __restrict__ Vp,
    int M, int K)
{
    const int sel = blockIdx.y >> 3;
    const int n0 = (blockIdx.y & 7) * 128;
    const u16* A = sel ? vb : qb;
    const u16* W = sel == 0 ? wqb : (sel == 1 ? wkb : wvb);
    const float* bias = sel == 0 ? bq : (sel == 1 ? bk : bv);
    u16* C = sel == 0 ? Qp : (sel == 1 ? Kp : Vp);
    const float cscale = sel == 0 ? QSCALE : 1.0f;

    __shared__ __align__(16) u16 As[2][128 * 32];
    __shared__ __align__(16) u16 Bs[2][128 * 32];

    const int tid  = threadIdx.x;
    const int wave = tid >> 6, lane = tid & 63;
    const int quad = lane >> 4, l16 = lane & 15;
    const int m0 = blockIdx.x * 128;
    const int wm = (wave >> 1) * 64, wn = (wave & 1) * 64;
    const int r0 = lane >> 2;
    const int c0 = (lane & 3) * 8;

    f32x4 acc[4][4] = {};

    GEMM_KLOOP(A, W)

#pragma unroll
    for (int mi = 0; mi < 4; ++mi) {
#pragma unroll
        for (int ni = 0; ni < 4; ++ni) {
            int col = n0 + wn + ni * 16 + l16;
            float bv2 = bias[col];
#pragma unroll
            for (int r = 0; r < 4; ++r) {
                int row = m0 + wm + mi * 16 + quad * 4 + r;
                C[(size_t)row * 1024 + col] = f2b((acc[mi][ni][r] + bv2) * cscale);
            }
        }
    }
}

// Output GEMM: C[M,N](fp32) = A[M,K](bf16) @ B[N,K]^T(bf16) + bias.
__global__ __launch_bounds__(256) void gemm_out(
    const u16* __restrict__ A, const u16* __restrict__ B,
    const float* __restrict__ bias, float* __restrict__ C,
    int M, int N, int K)
{
    __shared__ __align__(16) u16 As[2][128 * 32];
    __shared__ __align__(16) u16 Bs[2][128 * 32];

    const int tid  = threadIdx.x;
    const int wave = tid >> 6, lane = tid & 63;
    const int quad = lane >> 4, l16 = lane & 15;
    const int m0 = blockIdx.x * 128, n0 = blockIdx.y * 128;
    const int wm = (wave >> 1) * 64, wn = (wave & 1) * 64;
    const int r0 = lane >> 2;
    const int c0 = (lane & 3) * 8;

    f32x4 acc[4][4] = {};

    GEMM_KLOOP(A, B)

#pragma unroll
    for (int mi = 0; mi < 4; ++mi) {
#pragma unroll
        for (int ni = 0; ni < 4; ++ni) {
            int col = n0 + wn + ni * 16 + l16;
            float bv = bias[col];
#pragma unroll
            for (int r = 0; r < 4; ++r) {
                int row = m0 + wm + mi * 16 + quad * 4 + r;
                C[(size_t)row * N + col] = acc[mi][ni][r] + bv;
            }
        }
    }
}

// Transpose Vp[b*2048+l][1024] -> VT[(b*1024+d)*2048 + l].  64x64 bf16 tiles.
__global__ __launch_bounds__(256) void transpose_v(
    const u16* __restrict__ Vp, u16* __restrict__ VT)
{
    __shared__ u16 T[64 * 66];
    const int tid = threadIdx.x;
    const int l0 = blockIdx.x * 64, d0 = blockIdx.y * 64, b = blockIdx.z;

#pragma unroll
    for (int i = 0; i < 2; ++i) {
        int ch = tid + i * 256;
        int lrow = ch >> 3, c8 = (ch & 7) * 8;
        uint4 vv = *(const uint4*)(&Vp[((size_t)b * 2048 + l0 + lrow) * 1024 + d0 + c8]);
        const u16* vp = (const u16*)&vv;
#pragma unroll
        for (int j = 0; j < 8; ++j) T[lrow * 66 + c8 + j] = vp[j];
    }
    __syncthreads();
#pragma unroll
    for (int i = 0; i < 2; ++i) {
        int ch = tid + i * 256;
        int drow = ch >> 3, l8 = (ch & 7) * 8;
        u16 o[8];
#pragma unroll
        for (int j = 0; j < 8; ++j) o[j] = T[(l8 + j) * 66 + drow];
        *(uint4*)(&VT[((size_t)b * 1024 + d0 + drow) * 2048 + l0 + l8]) = *(uint4*)o;
    }
}

// Flash attention (Q pre-scaled so p = exp2(S); max-free). S transposed
// (mfma(kf,qf)); P packed (v_perm) and round-tripped through half-size
// wave-private Ps in two 32-k chunks; rowsum via 5th all-ones V^T tile.
// Shape: 32 q-rows/wave, 128/block, grid 1024 blocks = 4 blocks/CU.
// NO launch_bounds min-waves (r9's ",4" forced a catastrophic spill).
__global__ __launch_bounds__(256) void attn(
    const u16* __restrict__ Q, const u16* __restrict__ K,
    const u16* __restrict__ VT, u16* __restrict__ O,
    int LQ, int LK)
{
    const int tid  = threadIdx.x;
    const int wave = tid >> 6, lane = tid & 63;
    const int quad = lane >> 4, l16 = lane & 15;
    const int q0 = blockIdx.x * 128;
    const int bh = blockIdx.y;
    const int b = bh >> 4, h = bh & 15;
    const size_t qbase = ((size_t)b * LQ + q0) * 1024 + h * 64;
    const size_t kbase = ((size_t)b * LK) * 1024 + h * 64;
    const size_t vtbase = ((size_t)b * 1024 + h * 64) * 2048;

    __shared__ __align__(16) u16 Ks[64 * 72];        // [krow][d]
    __shared__ __align__(16) u16 VTs[80 * 72];       // [d][krow]; rows 64..79 = 1.0
    __shared__ __align__(16) u16 Ps[4][32 * 36];     // per-wave P [q][k-chunk of 32]

    for (int i = tid; i < 16 * 72; i += 256) VTs[64 * 72 + i] = 0x3F80;

    bf16x8 qf[2][2];
#pragma unroll
    for (int mi = 0; mi < 2; ++mi)
#pragma unroll
        for (int ks = 0; ks < 2; ++ks)
            qf[mi][ks] = *(const bf16x8*)(
                &Q[qbase + (size_t)(wave * 32 + mi * 16 + l16) * 1024 + ks * 32 + quad * 8]);

    f32x4 oacc[2][5] = {};   // [q-tile][4 d-tiles + 1 rowsum tile]

    for (int kt = 0; kt < LK; kt += 64) {
        __syncthreads();
#pragma unroll
        for (int i = 0; i < 2; ++i) {
            int ch = tid + i * 256;
            int row = ch >> 3, c8 = (ch & 7) * 8;
            *(uint4*)(&Ks[row * 72 + c8]) =
                *(const uint4*)(&K[kbase + (size_t)(kt + row) * 1024 + c8]);
            *(uint4*)(&VTs[row * 72 + c8]) =
                *(const uint4*)(&VT[vtbase + (size_t)row * 2048 + kt + c8]);
        }
        __syncthreads();

        // S^T tiles: st[ni][mi]; lane (quad,l16) reg r holds
        // S[q = mi*16+l16][k = ni*16+quad*4+r]
        f32x4 st[4][2] = {};
#pragma unroll
        for (int ks = 0; ks < 2; ++ks) {
            bf16x8 kf[4];
#pragma unroll
            for (int ni = 0; ni < 4; ++ni)
                kf[ni] = *(const bf16x8*)(&Ks[(ni * 16 + l16) * 72 + ks * 32 + quad * 8]);
#pragma unroll
            for (int ni = 0; ni < 4; ++ni)
#pragma unroll
                for (int mi = 0; mi < 2; ++mi)
                    st[ni][mi] = MFMA16(kf[ni], qf[mi][ks], st[ni][mi]);
        }

        // two 32-k chunks: pack P for chunk kh, then PV step kh (Ps reused)
#pragma unroll
        for (int kh = 0; kh < 2; ++kh) {
#pragma unroll
            for (int mi = 0; mi < 2; ++mi)
#pragma unroll
                for (int nj = 0; nj < 2; ++nj) {
                    int ni = kh * 2 + nj;
                    float p0 = __builtin_amdgcn_exp2f(st[ni][mi][0]);
                    float p1 = __builtin_amdgcn_exp2f(st[ni][mi][1]);
                    float p2 = __builtin_amdgcn_exp2f(st[ni][mi][2]);
                    float p3 = __builtin_amdgcn_exp2f(st[ni][mi][3]);
                    uint2 w;
                    w.x = pack2_trunc(p0, p1);
                    w.y = pack2_trunc(p2, p3);
                    *(uint2*)(&Ps[wave][(mi * 16 + l16) * 36 + nj * 16 + quad * 4]) = w;
                }
            // Ps wave-private: lgkmcnt orders wave-local LDS; no barrier.
            bf16x8 vf[5];
#pragma unroll
            for (int nd = 0; nd < 5; ++nd)
                vf[nd] = *(const bf16x8*)(&VTs[(nd * 16 + l16) * 72 + kh * 32 + quad * 8]);
#pragma unroll
            for (int mi = 0; mi < 2; ++mi) {
                bf16x8 pf = *(const bf16x8*)(&Ps[wave][(mi * 16 + l16) * 36 + quad * 8]);
#pragma unroll
                for (int nd = 0; nd < 5; ++nd)
                    oacc[mi][nd] = MFMA16(pf, vf[nd], oacc[mi][nd]);
            }
        }
    }

    // epilogue: divide by MFMA-computed row sums, store
#pragma unroll
    for (int mi = 0; mi < 2; ++mi)
#pragma unroll
        for (int r = 0; r < 4; ++r) {
            float inv = 1.0f / oacc[mi][4][r];
            int row = q0 + wave * 32 + mi * 16 + quad * 4 + r;
            size_t rb = ((size_t)b * LQ + row) * 1024 + h * 64;
#pragma unroll
            for (int nd = 0; nd < 4; ++nd)
                O[rb + nd * 16 + l16] = f2b(oacc[mi][nd][r] * inv);
        }
}

extern "C" void kernel_launch(void* const* d_in, const int* in_sizes, int n_in,
                              void* d_out, int out_size, void* d_ws, size_t ws_size,
                              hipStream_t stream) {
    const float* query = (const float*)d_in[0];
    const float* value = (const float*)d_in[1];
    const float* wq = (const float*)d_in[2];
    const float* bq = (const float*)d_in[3];
    const float* wk = (const float*)d_in[4];
    const float* bk = (const float*)d_in[5];
    const float* wv = (const float*)d_in[6];
    const float* bv = (const float*)d_in[7];
    const float* wo = (const float*)d_in[8];
    const float* bo = (const float*)d_in[9];

    const int B = 4, LQ = 2048, LK = 2048, D = 1024;
    const int M = B * LQ;                 // 8192
    const int mat = M * D;                // 8388608
    const int wsz = D * D;                // 1048576

    // ws (u16): qb vb | wqb wkb wvb wob | Qp Kp Vp VT  = 104 MB
    u16* ws  = (u16*)d_ws;
    u16* qb  = ws;
    u16* vb  = qb + mat;
    u16* wqb = vb + mat;
    u16* wkb = wqb + wsz;
    u16* wvb = wkb + wsz;
    u16* wob = wvb + wsz;
    u16* Qp  = wob + wsz;
    u16* Kp  = Qp + mat;
    u16* Vp  = Kp + mat;
    u16* VT  = Vp + mat;
    u16* Cp  = Vp;                        // Vp dead after transpose_v

    dim3 blk(256);

    cvt_f32_bf16<<<dim3(mat / 2048), blk, 0, stream>>>(query, qb, mat);
    cvt_f32_bf16<<<dim3(mat / 2048), blk, 0, stream>>>(value, vb, mat);
    cvt_f32_bf16<<<dim3(wsz / 2048), blk, 0, stream>>>(wq, wqb, wsz);
    cvt_f32_bf16<<<dim3(wsz / 2048), blk, 0, stream>>>(wk, wkb, wsz);
    cvt_f32_bf16<<<dim3(wsz / 2048), blk, 0, stream>>>(wv, wvb, wsz);
    cvt_f32_bf16<<<dim3(wsz / 2048), blk, 0, stream>>>(wo, wob, wsz);

    gemm_proj<<<dim3(M / 128, 24), blk, 0, stream>>>(
        qb, vb, wqb, wkb, wvb, bq, bk, bv, Qp, Kp, Vp, M, D);

    transpose_v<<<dim3(32, 16, 4), blk, 0, stream>>>(Vp, VT);

    attn<<<dim3(LQ / 128, B * 16), blk, 0, stream>>>(Qp, Kp, VT, Cp, LQ, LK);

    gemm_out<<<dim3(M / 128, D / 128), blk, 0, stream>>>(Cp, wob, bo, (float*)d_out, M, D, D);
}

// Round 11
// 366.277 us; speedup vs baseline: 2.1176x; 1.0607x over previous
//
#include <hip/hip_runtime.h>
#include <hip/hip_bf16.h>

typedef unsigned short u16;
typedef unsigned int u32;
typedef __attribute__((ext_vector_type(8))) short bf16x8;
typedef __attribute__((ext_vector_type(4))) float f32x4;

#define MFMA16(a, b, c) __builtin_amdgcn_mfma_f32_16x16x32_bf16(a, b, c, 0, 0, 0)

// fold of softmax scale into Q projection: exp(s/8) = 2^(s*0.125*log2(e))
#define QSCALE 0.18033688011112042f

__device__ inline u16 f2b(float f) {
    union { float f; unsigned int i; } v;
    v.f = f;
    unsigned int r = v.i + 0x7fffu + ((v.i >> 16) & 1u);
    return (u16)(r >> 16);
}
__device__ inline u32 fbits(float f) {
    union { float f; u32 i; } v; v.f = f; return v.i;
}
// pack two fp32 -> [bf16(f0) | bf16(f1)<<16], truncation, 1 v_perm_b32
__device__ inline u32 pack2_trunc(float f0, float f1) {
    return __builtin_amdgcn_perm(fbits(f1), fbits(f0), 0x07060302u);
}

// async global->LDS, 16B per lane (wave-uniform LDS base + lane*16 dest).
__device__ inline void glds16(const u16* g, u16* l) {
    __builtin_amdgcn_global_load_lds(
        (const __attribute__((address_space(1))) unsigned int*)g,
        (__attribute__((address_space(3))) unsigned int*)l, 16, 0, 0);
}

// fp32 -> bf16 (RNE), 8 elements per thread.
__global__ __launch_bounds__(256) void cvt_f32_bf16(
    const float* __restrict__ x, u16* __restrict__ y, int n)
{
    int i = (blockIdx.x * 256 + threadIdx.x) * 8;
    if (i >= n) return;
    float4 a = *(const float4*)(x + i);
    float4 b = *(const float4*)(x + i + 4);
    u16 o[8] = { f2b(a.x), f2b(a.y), f2b(a.z), f2b(a.w),
                 f2b(b.x), f2b(b.y), f2b(b.z), f2b(b.w) };
    *(uint4*)(y + i) = *(uint4*)o;
}

// Shared GEMM K-loop body: BK=64 as two BK=32 sub-tiles (glds16 lane-contiguity
// preserved per sub-tile). 32 MFMAs per barrier-pair.
#define GEMM_KLOOP(Aptr, Bptr)                                                  \
    for (int k0 = 0; k0 < K; k0 += 64) {                                        \
        __syncthreads();                                                        \
        {                                                                       \
            int ra = wave * 16 + r0;                                            \
            _Pragma("unroll")                                                   \
            for (int s = 0; s < 2; ++s) {                                       \
                int ks0 = k0 + s * 32;                                          \
                glds16(&Aptr[(size_t)(m0 + ra) * K + ks0 + c0],                 \
                       &As[s][ra * 32 + c0]);                                   \
                glds16(&Aptr[(size_t)(m0 + 64 + ra) * K + ks0 + c0],            \
                       &As[s][(64 + ra) * 32 + c0]);                            \
                glds16(&Bptr[(size_t)(n0 + ra) * K + ks0 + c0],                 \
                       &Bs[s][ra * 32 + c0]);                                   \
                glds16(&Bptr[(size_t)(n0 + 64 + ra) * K + ks0 + c0],            \
                       &Bs[s][(64 + ra) * 32 + c0]);                            \
            }                                                                   \
        }                                                                       \
        __syncthreads();                                                        \
        _Pragma("unroll")                                                       \
        for (int s = 0; s < 2; ++s) {                                           \
            bf16x8 af[4], bfr[4];                                               \
            _Pragma("unroll")                                                   \
            for (int mi = 0; mi < 4; ++mi)                                      \
                af[mi] = *(const bf16x8*)(&As[s][(wm + mi * 16 + l16) * 32 + quad * 8]); \
            _Pragma("unroll")                                                   \
            for (int ni = 0; ni < 4; ++ni)                                      \
                bfr[ni] = *(const bf16x8*)(&Bs[s][(wn + ni * 16 + l16) * 32 + quad * 8]); \
            _Pragma("unroll")                                                   \
            for (int mi = 0; mi < 4; ++mi)                                      \
                _Pragma("unroll")                                               \
                for (int ni = 0; ni < 4; ++ni)                                  \
                    acc[mi][ni] = MFMA16(af[mi], bfr[ni], acc[mi][ni]);         \
        }                                                                       \
    }

// Fused Q/K/V projections. sel = blockIdx.y/8 picks {src, weight, bias, dst, scale}.
__global__ __launch_bounds__(256) void gemm_proj(
    const u16* __restrict__ qb, const u16* __restrict__ vb,
    const u16* __restrict__ wqb, const u16* __restrict__ wkb,
    const u16* __restrict__ wvb,
    const float* __restrict__ bq, const float* __restrict__ bk,
    const float* __restrict__ bv,
    u16* __restrict__ Qp, u16* __restrict__ Kp, u16* __restrict__ Vp,
    int M, int K)
{
    const int sel = blockIdx.y >> 3;
    const int n0 = (blockIdx.y & 7) * 128;
    const u16* A = sel ? vb : qb;
    const u16* W = sel == 0 ? wqb : (sel == 1 ? wkb : wvb);
    const float* bias = sel == 0 ? bq : (sel == 1 ? bk : bv);
    u16* C = sel == 0 ? Qp : (sel == 1 ? Kp : Vp);
    const float cscale = sel == 0 ? QSCALE : 1.0f;

    __shared__ __align__(16) u16 As[2][128 * 32];
    __shared__ __align__(16) u16 Bs[2][128 * 32];

    const int tid  = threadIdx.x;
    const int wave = tid >> 6, lane = tid & 63;
    const int quad = lane >> 4, l16 = lane & 15;
    const int m0 = blockIdx.x * 128;
    const int wm = (wave >> 1) * 64, wn = (wave & 1) * 64;
    const int r0 = lane >> 2;
    const int c0 = (lane & 3) * 8;

    f32x4 acc[4][4] = {};

    GEMM_KLOOP(A, W)

#pragma unroll
    for (int mi = 0; mi < 4; ++mi) {
#pragma unroll
        for (int ni = 0; ni < 4; ++ni) {
            int col = n0 + wn + ni * 16 + l16;
            float bv2 = bias[col];
#pragma unroll
            for (int r = 0; r < 4; ++r) {
                int row = m0 + wm + mi * 16 + quad * 4 + r;
                C[(size_t)row * 1024 + col] = f2b((acc[mi][ni][r] + bv2) * cscale);
            }
        }
    }
}

// Output GEMM: C[M,N](fp32) = A[M,K](bf16) @ B[N,K]^T(bf16) + bias.
__global__ __launch_bounds__(256) void gemm_out(
    const u16* __restrict__ A, const u16* __restrict__ B,
    const float* __restrict__ bias, float* __restrict__ C,
    int M, int N, int K)
{
    __shared__ __align__(16) u16 As[2][128 * 32];
    __shared__ __align__(16) u16 Bs[2][128 * 32];

    const int tid  = threadIdx.x;
    const int wave = tid >> 6, lane = tid & 63;
    const int quad = lane >> 4, l16 = lane & 15;
    const int m0 = blockIdx.x * 128, n0 = blockIdx.y * 128;
    const int wm = (wave >> 1) * 64, wn = (wave & 1) * 64;
    const int r0 = lane >> 2;
    const int c0 = (lane & 3) * 8;

    f32x4 acc[4][4] = {};

    GEMM_KLOOP(A, B)

#pragma unroll
    for (int mi = 0; mi < 4; ++mi) {
#pragma unroll
        for (int ni = 0; ni < 4; ++ni) {
            int col = n0 + wn + ni * 16 + l16;
            float bv = bias[col];
#pragma unroll
            for (int r = 0; r < 4; ++r) {
                int row = m0 + wm + mi * 16 + quad * 4 + r;
                C[(size_t)row * N + col] = acc[mi][ni][r] + bv;
            }
        }
    }
}

// Transpose Vp[b*2048+l][1024] -> VT[(b*1024+d)*2048 + l].  64x64 bf16 tiles.
__global__ __launch_bounds__(256) void transpose_v(
    const u16* __restrict__ Vp, u16* __restrict__ VT)
{
    __shared__ u16 T[64 * 66];
    const int tid = threadIdx.x;
    const int l0 = blockIdx.x * 64, d0 = blockIdx.y * 64, b = blockIdx.z;

#pragma unroll
    for (int i = 0; i < 2; ++i) {
        int ch = tid + i * 256;
        int lrow = ch >> 3, c8 = (ch & 7) * 8;
        uint4 vv = *(const uint4*)(&Vp[((size_t)b * 2048 + l0 + lrow) * 1024 + d0 + c8]);
        const u16* vp = (const u16*)&vv;
#pragma unroll
        for (int j = 0; j < 8; ++j) T[lrow * 66 + c8 + j] = vp[j];
    }
    __syncthreads();
#pragma unroll
    for (int i = 0; i < 2; ++i) {
        int ch = tid + i * 256;
        int drow = ch >> 3, l8 = (ch & 7) * 8;
        u16 o[8];
#pragma unroll
        for (int j = 0; j < 8; ++j) o[j] = T[(l8 + j) * 66 + drow];
        *(uint4*)(&VT[((size_t)b * 1024 + d0 + drow) * 2048 + l0 + l8]) = *(uint4*)o;
    }
}

// Flash attention, r8 geometry (64 q-rows/wave, 256 q/block, grid 512) +
// halved chunked Ps + ASYNC glds16 K/V staging with XOR-swizzled LDS layout:
// LDS dest is forced base+lane*16, so swizzle is applied to the GLOBAL chunk
// index (lane l loads global chunk (l&7)^(l>>3)); readers address chunk
// c^(row&7) -> max 2-way bank aliasing (free). Ones rowsum tile is
// permutation-invariant (all 1.0), no swizzle handling needed.
__global__ __launch_bounds__(256) void attn(
    const u16* __restrict__ Q, const u16* __restrict__ K,
    const u16* __restrict__ VT, u16* __restrict__ O,
    int LQ, int LK)
{
    const int tid  = threadIdx.x;
    const int wave = tid >> 6, lane = tid & 63;
    const int quad = lane >> 4, l16 = lane & 15;
    const int q0 = blockIdx.x * 256;
    const int bh = blockIdx.y;
    const int b = bh >> 4, h = bh & 15;
    const size_t qbase = ((size_t)b * LQ + q0) * 1024 + h * 64;
    const size_t kbase = ((size_t)b * LK) * 1024 + h * 64;
    const size_t vtbase = ((size_t)b * 1024 + h * 64) * 2048;

    __shared__ __align__(16) u16 Ks[64 * 64];        // [krow][d], swizzled chunks
    __shared__ __align__(16) u16 VTs[80 * 64];       // [d][krow] swizzled; 64..79 ones
    __shared__ __align__(16) u16 Ps[4][64 * 36];     // per-wave P [q][k-chunk of 32]

    for (int i = tid; i < 16 * 64; i += 256) VTs[64 * 64 + i] = 0x3F80;

    // staging lane geometry: 8 rows per glds16 instr per wave
    const int s8 = lane >> 3;          // sub-row 0..7
    const int sc = (lane & 7) ^ s8;    // swizzled global chunk index
    // fragment-read swizzle: row&7 == l16&7 for all tiles (tile base % 16 == 0)
    const int rx = l16 & 7;

    bf16x8 qf[4][2];
#pragma unroll
    for (int mi = 0; mi < 4; ++mi)
#pragma unroll
        for (int ks = 0; ks < 2; ++ks)
            qf[mi][ks] = *(const bf16x8*)(
                &Q[qbase + (size_t)(wave * 64 + mi * 16 + l16) * 1024 + ks * 32 + quad * 8]);

    f32x4 oacc[4][5] = {};   // [q-tile][4 d-tiles + 1 rowsum tile]

    for (int kt = 0; kt < LK; kt += 64) {
        __syncthreads();
#pragma unroll
        for (int i = 0; i < 2; ++i) {
            int row = wave * 16 + i * 8 + s8;       // k-row (K) / d-row (VT)
            glds16(&K[kbase + (size_t)(kt + row) * 1024 + sc * 8],
                   &Ks[(wave * 16 + i * 8) * 64]);
            glds16(&VT[vtbase + (size_t)row * 2048 + kt + sc * 8],
                   &VTs[(wave * 16 + i * 8) * 64]);
        }
        __syncthreads();   // vmcnt(0) drain + publish

        // S^T tiles: st[ni][mi]; lane (quad,l16) reg r holds
        // S[q = mi*16+l16][k = ni*16+quad*4+r]
        f32x4 st[4][4] = {};
#pragma unroll
        for (int ks = 0; ks < 2; ++ks) {
            bf16x8 kf[4];
#pragma unroll
            for (int ni = 0; ni < 4; ++ni)
                kf[ni] = *(const bf16x8*)(
                    &Ks[(ni * 16 + l16) * 64 + (((ks * 4 + quad) ^ rx) * 8)]);
#pragma unroll
            for (int ni = 0; ni < 4; ++ni)
#pragma unroll
                for (int mi = 0; mi < 4; ++mi)
                    st[ni][mi] = MFMA16(kf[ni], qf[mi][ks], st[ni][mi]);
        }

        // two 32-k chunks: pack P for chunk kh, then PV step kh (Ps reused)
#pragma unroll
        for (int kh = 0; kh < 2; ++kh) {
#pragma unroll
            for (int mi = 0; mi < 4; ++mi)
#pragma unroll
                for (int nj = 0; nj < 2; ++nj) {
                    int ni = kh * 2 + nj;
                    float p0 = __builtin_amdgcn_exp2f(st[ni][mi][0]);
                    float p1 = __builtin_amdgcn_exp2f(st[ni][mi][1]);
                    float p2 = __builtin_amdgcn_exp2f(st[ni][mi][2]);
                    float p3 = __builtin_amdgcn_exp2f(st[ni][mi][3]);
                    uint2 w;
                    w.x = pack2_trunc(p0, p1);
                    w.y = pack2_trunc(p2, p3);
                    *(uint2*)(&Ps[wave][(mi * 16 + l16) * 36 + nj * 16 + quad * 4]) = w;
                }
            // Ps wave-private: lgkmcnt orders wave-local LDS; no barrier.
            bf16x8 vf[5];
#pragma unroll
            for (int nd = 0; nd < 5; ++nd)
                vf[nd] = *(const bf16x8*)(
                    &VTs[(nd * 16 + l16) * 64 + (((kh * 4 + quad) ^ rx) * 8)]);
#pragma unroll
            for (int mi = 0; mi < 4; ++mi) {
                bf16x8 pf = *(const bf16x8*)(&Ps[wave][(mi * 16 + l16) * 36 + quad * 8]);
#pragma unroll
                for (int nd = 0; nd < 5; ++nd)
                    oacc[mi][nd] = MFMA16(pf, vf[nd], oacc[mi][nd]);
            }
        }
    }

    // epilogue: divide by MFMA-computed row sums, store
#pragma unroll
    for (int mi = 0; mi < 4; ++mi)
#pragma unroll
        for (int r = 0; r < 4; ++r) {
            float inv = 1.0f / oacc[mi][4][r];
            int row = q0 + wave * 64 + mi * 16 + quad * 4 + r;
            size_t rb = ((size_t)b * LQ + row) * 1024 + h * 64;
#pragma unroll
            for (int nd = 0; nd < 4; ++nd)
                O[rb + nd * 16 + l16] = f2b(oacc[mi][nd][r] * inv);
        }
}

extern "C" void kernel_launch(void* const* d_in, const int* in_sizes, int n_in,
                              void* d_out, int out_size, void* d_ws, size_t ws_size,
                              hipStream_t stream) {
    const float* query = (const float*)d_in[0];
    const float* value = (const float*)d_in[1];
    const float* wq = (const float*)d_in[2];
    const float* bq = (const float*)d_in[3];
    const float* wk = (const float*)d_in[4];
    const float* bk = (const float*)d_in[5];
    const float* wv = (const float*)d_in[6];
    const float* bv = (const float*)d_in[7];
    const float* wo = (const float*)d_in[8];
    const float* bo = (const float*)d_in[9];

    const int B = 4, LQ = 2048, LK = 2048, D = 1024;
    const int M = B * LQ;                 // 8192
    const int mat = M * D;                // 8388608
    const int wsz = D * D;                // 1048576

    // ws (u16): qb vb | wqb wkb wvb wob | Qp Kp Vp VT  = 104 MB
    u16* ws  = (u16*)d_ws;
    u16* qb  = ws;
    u16* vb  = qb + mat;
    u16* wqb = vb + mat;
    u16* wkb = wqb + wsz;
    u16* wvb = wkb + wsz;
    u16* wob = wvb + wsz;
    u16* Qp  = wob + wsz;
    u16* Kp  = Qp + mat;
    u16* Vp  = Kp + mat;
    u16* VT  = Vp + mat;
    u16* Cp  = Vp;                        // Vp dead after transpose_v

    dim3 blk(256);

    cvt_f32_bf16<<<dim3(mat / 2048), blk, 0, stream>>>(query, qb, mat);
    cvt_f32_bf16<<<dim3(mat / 2048), blk, 0, stream>>>(value, vb, mat);
    cvt_f32_bf16<<<dim3(wsz / 2048), blk, 0, stream>>>(wq, wqb, wsz);
    cvt_f32_bf16<<<dim3(wsz / 2048), blk, 0, stream>>>(wk, wkb, wsz);
    cvt_f32_bf16<<<dim3(wsz / 2048), blk, 0, stream>>>(wv, wvb, wsz);
    cvt_f32_bf16<<<dim3(wsz / 2048), blk, 0, stream>>>(wo, wob, wsz);

    gemm_proj<<<dim3(M / 128, 24), blk, 0, stream>>>(
        qb, vb, wqb, wkb, wvb, bq, bk, bv, Qp, Kp, Vp, M, D);

    transpose_v<<<dim3(32, 16, 4), blk, 0, stream>>>(Vp, VT);

    attn<<<dim3(LQ / 256, B * 16), blk, 0, stream>>>(Qp, Kp, VT, Cp, LQ, LK);

    gemm_out<<<dim3(M / 128, D / 128), blk, 0, stream>>>(Cp, wob, bo, (float*)d_out, M, D, D);
}